// Round 14
// baseline (2820.540 us; speedup 1.0000x reference)
//
#include <hip/hip_runtime.h>
#include <stdint.h>

#define BETA 0.9f

typedef unsigned short u16;
typedef unsigned char u8;
typedef signed char i8;
typedef int i32x4 __attribute__((ext_vector_type(4)));

// async global->LDS, 16B per lane; lds ptr is wave-uniform base (+lane*16 by HW)
__device__ __forceinline__ void async_copy16(const void* g, void* l) {
  __builtin_amdgcn_global_load_lds(
      (const __attribute__((address_space(1))) uint32_t*)g,
      (__attribute__((address_space(3))) uint32_t*)l, 16, 0, 0);
}

// ---------------------------------------------------------------------------
// prep: 3-way int8 fixed-point split of W2/W3 (HW-verified exact, r6/r12/r13):
//   d0 = rint(w*2^11); d1 = rint(r1*2^18); d2 = rint(r2*2^25); res <= 2^-26
// Reconstruction: w*2^25 ~= ((d0<<7)+d1)<<7 + d2 (exact i32 fold).
// Layout A[part][cp][ct][tap][co64][ci64] i8; 12KB DMA blocks; 16-i8 granule
// XOR-swizzled by ((col>>1)&3) for conflict-free b128 LDS reads.
// ---------------------------------------------------------------------------
__global__ void prep_kernel(const float* __restrict__ W2, const float* __restrict__ W3,
                            const float* __restrict__ fw1, const float* __restrict__ fw2,
                            i8* __restrict__ A2c, i8* __restrict__ A3c,
                            float* __restrict__ fw1T, float* __restrict__ fw2T) {
  int o = blockIdx.x * 256 + threadIdx.x;
  if (o < 98304) {  // W2: (tap, co, ci), 3*128*256
    int tap = o >> 15, r = o & 32767, co = r >> 8, ci = r & 255;
    float w = W2[(co * 256 + ci) * 3 + tap];
    float d0 = __builtin_rintf(w * 0x1p11f);
    float r1 = w - d0 * 0x1p-11f;
    float d1 = __builtin_rintf(r1 * 0x1p18f);
    float r2 = r1 - d1 * 0x1p-18f;
    float d2 = __builtin_rintf(r2 * 0x1p25f);
    int cp = ci >> 6, cl = ci & 63;
    int ct = co >> 6, col = co & 63;
    int gs = ((cl >> 4) ^ ((col >> 1) & 3)) & 3;
    int pos = gs * 16 + (cl & 15);
    size_t base = ((size_t)((0 * 4 + cp) * 2 + ct) * 3 + tap) * 64 * 64 + col * 64 + pos;
    size_t pstride = (size_t)4 * 2 * 3 * 64 * 64;  // 98304
    A2c[base] = (i8)(int)d0;
    A2c[pstride + base] = (i8)(int)d1;
    A2c[2 * pstride + base] = (i8)(int)d2;
  }
  int o2 = o - 98304;  // W3: (tap, co, ci), 3*64*128 (NCT=1)
  if (o2 >= 0 && o2 < 24576) {
    int tap = o2 >> 13, r = o2 & 8191, co = r >> 7, ci = r & 127;
    float w = W3[(co * 128 + ci) * 3 + tap];
    float d0 = __builtin_rintf(w * 0x1p11f);
    float r1 = w - d0 * 0x1p-11f;
    float d1 = __builtin_rintf(r1 * 0x1p18f);
    float r2 = r1 - d1 * 0x1p-18f;
    float d2 = __builtin_rintf(r2 * 0x1p25f);
    int cp = ci >> 6, cl = ci & 63;
    int gs = ((cl >> 4) ^ ((co >> 1) & 3)) & 3;
    int pos = gs * 16 + (cl & 15);
    size_t base = ((size_t)(0 * 2 + cp) * 3 + tap) * 64 * 64 + co * 64 + pos;
    size_t pstride = (size_t)2 * 3 * 64 * 64;  // 24576
    A3c[base] = (i8)(int)d0;
    A3c[pstride + base] = (i8)(int)d1;
    A3c[2 * pstride + base] = (i8)(int)d2;
  }
  int o3 = o - (98304 + 24576);
  if (o3 >= 0 && o3 < 25600) {
    int f = o3 / 100, i = o3 % 100;
    fw1T[o3] = fw1[i * 256 + f];
  }
  int o4 = o - (98304 + 24576 + 25600);
  if (o4 >= 0 && o4 < 4000) {
    int i = o4 / 40, j = o4 % 40;
    fw2T[o4] = fw2[j * 100 + i];
  }
}

// ---------------------------------------------------------------------------
// conv1 (2->256, K=5, pad=2) + LIF1 via wave ballot.
// Block (b, l-octet); wave w holds co = 64w + lane, iterates 8 l's.
// __ballot(spike) at step t IS the byte-transpose: u64 = 8 bytes for
// g = 8w..8w+8 at (l,t). Layout SBT2[b][l][t][g(32)] (t before g).
// ---------------------------------------------------------------------------
__global__ __launch_bounds__(256) void conv1_lif_kernel(
    const float* __restrict__ x, const float* __restrict__ W1,
    const float* __restrict__ b1, u8* __restrict__ SBT2) {
  __shared__ float xl[2][12];
  int b = blockIdx.x, lb8 = blockIdx.y * 8;
  int tid = threadIdx.x, lane = tid & 63, w = tid >> 6;
  int co = w * 64 + lane;
  if (tid < 24) {
    int ci = tid / 12, idx = tid % 12, lg = lb8 + idx - 2;
    xl[ci][idx] = (lg >= 0 && lg < 128) ? x[(b * 2 + ci) * 128 + lg] : 0.0f;
  }
  float wgt[2][5];
#pragma unroll
  for (int ci = 0; ci < 2; ++ci)
#pragma unroll
    for (int k = 0; k < 5; ++k) wgt[ci][k] = W1[(co * 2 + ci) * 5 + k];
  float bias = b1[co];
  __syncthreads();
  float cur[8];
#pragma unroll
  for (int j = 0; j < 8; ++j) {
    float a = bias;
#pragma unroll
    for (int ci = 0; ci < 2; ++ci)
#pragma unroll
      for (int k = 0; k < 5; ++k) a += wgt[ci][k] * xl[ci][j + k];
    cur[j] = a;
  }
  unsigned long long st0 = 0ull, st1 = 0ull;
#pragma unroll
  for (int l = 0; l < 8; ++l) {
    float m = 0.f, sp = 0.f;
#pragma unroll
    for (int t = 0; t < 16; ++t) {
      m = BETA * m + cur[l] - sp;
      bool s = m > 1.0f;
      unsigned long long bal = __ballot(s);
      int p = l * 16 + t;
      if ((p & 63) == lane) {
        if (p < 64) st0 = bal; else st1 = bal;
      }
      sp = s ? 1.0f : 0.0f;
    }
  }
  int l0 = lane >> 4, t0 = lane & 15;
  *(uint2*)(SBT2 + ((size_t)(b * 128 + lb8 + l0) * 16 + t0) * 32 + w * 8) =
      *(uint2*)&st0;
  *(uint2*)(SBT2 + ((size_t)(b * 128 + lb8 + 4 + l0) * 16 + t0) * 32 + w * 8) =
      *(uint2*)&st1;
}

// ---------------------------------------------------------------------------
// i8 MFMA conv (CIN->COUT, K=3, pad=1) + LIF.  [r13 minus the B-LDS trip]
// Part-major i8 3-split, single i32 acc, exact <<7 folds; boustrophedon cp
// order (Bf regs persist across part-boundary skips).
// B: per staged chunk, each lane loads 10 u16 from SBT[b][l][t][g] (one
//    contiguous u16 = its 16-ci fragment source; L3-hot) and expands
//    in-register via nibble mul-spread. NO B LDS, ONE barrier per v.
// A: async dbuf LDS 12KB/block, r7 granule swizzle. 3 blocks/CU.
// ---------------------------------------------------------------------------
template <int CIN, int COUT, bool SBTOUT>
__global__ __launch_bounds__(256, 3) void conv_mfma_kernel(
    const u8* __restrict__ SBT, const i8* __restrict__ Agc,
    const float* __restrict__ bias, void* __restrict__ outp) {
  constexpr int NCP = CIN / 64;            // chunk-pairs (64-ci units)
  constexpr int LNCP = (NCP == 4) ? 2 : 1;
  constexpr int NVIRT = 3 * NCP;
  constexpr int NCT = COUT / 64;
  constexpr int MT = 2, NT = 8;
  constexpr int GB = CIN / 8;              // g count (bytes per (l,t) row)
  constexpr int ABYTES = 3 * 64 * 64;      // 12288 per (part,cp,ct) A block
  constexpr int AW = ABYTES / 4;
  constexpr int AISS = AW / 1024;          // 3
  __shared__ __align__(16) char lds[2 * ABYTES];   // A dbuf; epilogue reuses

  int b = blockIdx.x, lb = blockIdx.y * 16, ct = blockIdx.z;
  int tid = threadIdx.x, lane = tid & 63, wid = tid >> 6;
  int wx = wid & 1, wy = wid >> 1;
  int q = lane >> 4, xx = lane & 15;
  int mloc = wy * 32;
  int lw = lb + wx * 8;
  int gs16 = ((q ^ ((xx >> 1) & 3)) & 3) * 16;  // A swizzled granule (bytes)

  i32x4 acc[MT][NT];
#pragma unroll
  for (int mt = 0; mt < MT; ++mt)
#pragma unroll
    for (int nt = 0; nt < NT; ++nt) acc[mt][nt] = (i32x4){0, 0, 0, 0};

  // per-lane B source: u16 at ((b*128+l)*16 + t=xx)*GB + cp*8 + 2q
  auto load_byt = [&](int cp, uint32_t* dst) {
#pragma unroll
    for (int u = 0; u < 10; ++u) {
      int l_in = lw + u - 1;
      dst[u] = ((unsigned)l_in < 128u)
                   ? (uint32_t)*(const u16*)(SBT +
                         ((size_t)(b * 128 + l_in) * 16 + xx) * GB + cp * 8 + 2 * q)
                   : 0u;
    }
  };
  auto expand = [&](uint32_t y) -> i32x4 {
    uint32_t b0 = y & 0xFFu, b1 = (y >> 8) & 0xFFu;
    i32x4 r;
    r.x = (int)(((b0 & 0xFu) * 0x204081u) & 0x01010101u);
    r.y = (int)(((b0 >> 4) * 0x204081u) & 0x01010101u);
    r.z = (int)(((b1 & 0xFu) * 0x204081u) & 0x01010101u);
    r.w = (int)(((b1 >> 4) * 0x204081u) & 0x01010101u);
    return r;
  };
  auto ablock = [&](int v) -> size_t {
    int p = v >> LNCP, j = v & (NCP - 1);
    int cp = (p & 1) ? (NCP - 1 - j) : j;
    return ((size_t)(p * NCP + cp) * NCT + ct) * (size_t)ABYTES;
  };

  // prologue: B bytes for cp 0; A-DMA for v=0
  uint32_t byt[10];
  load_byt(0, byt);
  {
    const char* gsrc = (const char*)Agc + (size_t)wid * AW + lane * 16 + ablock(0);
    char* ldst = lds + wid * AW;
#pragma unroll
    for (int i = 0; i < AISS; ++i) async_copy16(gsrc + i * 1024, ldst + i * 1024);
  }

  i32x4 Bf[10];
  for (int v = 0; v < NVIRT; ++v) {
    int p = v >> LNCP, j = v & (NCP - 1);
    bool stg = (v == 0) || (j != 0);
    __syncthreads();  // drains A-DMA(v); swaps buffers
    if (v + 1 < NVIRT) {
      const char* gsrc = (const char*)Agc + (size_t)wid * AW + lane * 16 + ablock(v + 1);
      char* ldst = lds + ((v + 1) & 1) * ABYTES + wid * AW;
#pragma unroll
      for (int i = 0; i < AISS; ++i) async_copy16(gsrc + i * 1024, ldst + i * 1024);
    }
    if (stg) {
      // expand current chunk's fragments (regs persist across skips)
#pragma unroll
      for (int u = 0; u < 10; ++u) Bf[u] = expand(byt[u]);
      // prefetch sources for the next staged cp
      int jn = j + 1, pn = p;
      if (jn == NCP) { pn = p + 1; jn = 1; }
      if (pn < 3) {
        int cpn = (pn & 1) ? (NCP - 1 - jn) : jn;
        load_byt(cpn, byt);
      }
    }
    if (j == 0 && p > 0) {  // part boundary: exact fold
#pragma unroll
      for (int mt = 0; mt < MT; ++mt)
#pragma unroll
        for (int nt = 0; nt < NT; ++nt) acc[mt][nt] = acc[mt][nt] << 7;
    }
    const i8* Asv = (const i8*)(lds + (v & 1) * ABYTES);
#pragma unroll
    for (int tap = 0; tap < 3; ++tap)
#pragma unroll
      for (int mt = 0; mt < MT; ++mt) {
        i32x4 Af = *(const i32x4*)(Asv + (tap * 64 + mloc + mt * 16 + xx) * 64 + gs16);
#pragma unroll
        for (int nt = 0; nt < NT; ++nt)
          acc[mt][nt] = __builtin_amdgcn_mfma_i32_16x16x64_i8(
              Af, Bf[nt + tap], acc[mt][nt], 0, 0, 0);
      }
  }
  __syncthreads();

  // epilogue: scale 2^-25, per-wave scr transpose (stride 19), LIF, pack
  float* scr = (float*)(void*)lds + wid * 1216;  // 64 rows x 19 words
  u16* blx = (u16*)(lds + 19456);  // SBTOUT: [16 l][64 co]; else [64 co][16 l]
#pragma unroll
  for (int mt = 0; mt < MT; ++mt) {
#pragma unroll
    for (int h = 0; h < 2; ++h) {
#pragma unroll
      for (int u2 = 0; u2 < 4; ++u2)
#pragma unroll
        for (int r = 0; r < 4; ++r)
          scr[(u2 * 16 + q * 4 + r) * 19 + xx] =
              (float)acc[mt][h * 4 + u2][r] * 0x1p-25f;
      __syncthreads();
      int col = mloc + mt * 16 + xx;
      float bc = bias[ct * 64 + col];
      const float* rowp = scr + (q * 16 + xx) * 19;
      float mm = 0.f, sp = 0.f;
      uint32_t bits = 0;
#pragma unroll
      for (int t = 0; t < 16; ++t) {
        float cur = rowp[t] + bc;
        mm = BETA * mm + cur - sp;
        bool s = mm > 1.0f;
        bits |= ((uint32_t)s) << t;
        sp = s ? 1.0f : 0.0f;
      }
      int ll = wx * 8 + h * 4 + q;
      if constexpr (SBTOUT) blx[ll * 64 + col] = (u16)bits;
      else                  blx[col * 16 + ll] = (u16)bits;
      __syncthreads();
    }
  }

  if constexpr (SBTOUT) {
    // thread = (l, t): build 8 bytes (g 0..8) -> [b][l][t][16] at ct*8
    int l = tid >> 4, t = tid & 15;
    uint4 rows[8];
#pragma unroll
    for (int r = 0; r < 8; ++r) rows[r] = *(const uint4*)(blx + l * 64 + r * 8);
    uint32_t lo = 0, hi = 0;
#pragma unroll
    for (int g = 0; g < 8; ++g) {
      uint32_t wv[4] = {rows[g].x, rows[g].y, rows[g].z, rows[g].w};
      uint32_t by = 0;
#pragma unroll
      for (int j2 = 0; j2 < 8; ++j2) {
        uint32_t h16 = (wv[j2 >> 1] >> (16 * (j2 & 1))) & 0xFFFFu;
        by |= ((h16 >> t) & 1u) << j2;
      }
      if (g < 4) lo |= by << (8 * g);
      else       hi |= by << (8 * (g - 4));
    }
    *(uint2*)((u8*)outp + ((size_t)(b * 128 + lb + l) * 16 + t) * 16 + ct * 8) =
        make_uint2(lo, hi);
  } else {
    if (tid < 128) {  // 64 co x 2 halves of 8 l (16B each) -> u16 rows
      int col = tid >> 1, hf = tid & 1;
      uint4 v = *(const uint4*)(blx + col * 16 + hf * 8);
      *(uint4*)((u16*)outp + ((size_t)b * COUT + ct * 64 + col) * 128 + lb + hf * 8) = v;
    }
  }
}

// ---------------------------------------------------------------------------
// head: conv4 (64->2) + LIF4; fc1 (256->100) split across 2 f-halves (200
// active threads, LDS partial reduce) + LIF5; fc2 accumulated (popcount).
// ---------------------------------------------------------------------------
__global__ __launch_bounds__(256) void head_kernel(
    const u16* __restrict__ s3bits, const float* __restrict__ W4,
    const float* __restrict__ b4, const float* __restrict__ fw1T,
    const float* __restrict__ fb1, const float* __restrict__ fw2T,
    const float* __restrict__ fb2, float* __restrict__ out) {
  __shared__ u16 s3l[64][130];
  __shared__ float W4l[384];
  __shared__ u16 flat4[256];
  __shared__ u16 s5b[100];
  int b = blockIdx.x, tid = threadIdx.x;

  for (int i = tid; i < 64 * 130; i += 256) {
    int ci = i / 130, idx = i % 130, lg = idx - 1;
    s3l[ci][idx] = (lg >= 0 && lg < 128) ? s3bits[((size_t)b * 64 + ci) * 128 + lg] : (u16)0;
  }
  for (int i = tid; i < 384; i += 256) W4l[i] = W4[i];
  __syncthreads();

  {
    int co = tid >> 7, l = tid & 127;
    float acc4[16];
#pragma unroll
    for (int t = 0; t < 16; ++t) acc4[t] = 0.f;
    for (int ci = 0; ci < 64; ++ci) {
#pragma unroll
      for (int k = 0; k < 3; ++k) {
        float wv = W4l[(co * 64 + ci) * 3 + k];
        uint32_t msk = s3l[ci][l + k];
#pragma unroll
        for (int t = 0; t < 16; ++t)
          acc4[t] = fmaf(wv, (float)((msk >> t) & 1u), acc4[t]);
      }
    }
    float bc = b4[co];
    float m = 0.f, sp = 0.f;
    uint32_t bits = 0;
#pragma unroll
    for (int t = 0; t < 16; ++t) {
      m = BETA * m + (acc4[t] + bc) - sp;
      bool s = m > 1.0f;
      bits |= ((uint32_t)s) << t;
      sp = s ? 1.0f : 0.0f;
    }
    flat4[tid] = (u16)bits;
  }
  __syncthreads();

  float* part5 = (float*)&s3l[0][0];  // s3l dead; 100*16*4 = 6400 B
  float acc5[16];
#pragma unroll
  for (int t = 0; t < 16; ++t) acc5[t] = 0.f;
  int n5 = tid % 100, h5 = tid / 100;
  if (tid < 200) {
    const float* wp = fw1T + (h5 * 128) * 100 + n5;
    for (int f = 0; f < 128; ++f) {
      float wv = wp[f * 100];
      uint32_t msk = flat4[h5 * 128 + f];
#pragma unroll
      for (int t = 0; t < 16; ++t)
        acc5[t] = fmaf(wv, (float)((msk >> t) & 1u), acc5[t]);
    }
    if (h5 == 1) {
#pragma unroll
      for (int t = 0; t < 16; ++t) part5[n5 * 16 + t] = acc5[t];
    }
  }
  __syncthreads();
  if (tid < 100) {
    float bc = fb1[tid];
    float m = 0.f, sp = 0.f;
    uint32_t bits = 0;
#pragma unroll
    for (int t = 0; t < 16; ++t) {
      float cur = acc5[t] + part5[tid * 16 + t] + bc;
      m = BETA * m + cur - sp;
      bool s = m > 1.0f;
      bits |= ((uint32_t)s) << t;
      sp = s ? 1.0f : 0.0f;
    }
    s5b[tid] = (u16)bits;
  }
  __syncthreads();

  if (tid < 40) {
    float a = 0.f;
    for (int i = 0; i < 100; ++i) {
      float wv = fw2T[i * 40 + tid];
      a = fmaf(wv, (float)__popc((uint32_t)s5b[i]), a);
    }
    out[b * 40 + tid] = a * 0.0625f + fb2[tid];
  }
}

// ---------------------------------------------------------------------------
extern "C" void kernel_launch(void* const* d_in, const int* in_sizes, int n_in,
                              void* d_out, int out_size, void* d_ws, size_t ws_size,
                              hipStream_t stream) {
  const float* x   = (const float*)d_in[0];
  const float* W1  = (const float*)d_in[1];
  const float* b1  = (const float*)d_in[2];
  const float* W2  = (const float*)d_in[3];
  const float* b2  = (const float*)d_in[4];
  const float* W3  = (const float*)d_in[5];
  const float* b3  = (const float*)d_in[6];
  const float* W4  = (const float*)d_in[7];
  const float* b4  = (const float*)d_in[8];
  const float* fw1 = (const float*)d_in[9];
  const float* fb1 = (const float*)d_in[10];
  const float* fw2 = (const float*)d_in[11];
  const float* fb2 = (const float*)d_in[12];
  float* out = (float*)d_out;

  char* ws = (char*)d_ws;
  i8*    A2c  = (i8*)(ws);                        // 294912 B [part][cp][ct][tap][co64][ci64]
  i8*    A3c  = (i8*)(ws + 294912);               //  73728 B
  float* fw1T = (float*)(ws + 368640);            // 102400 B
  float* fw2T = (float*)(ws + 471040);            //  16000 B (pad to 487424)
  u8*    SBT2 = (u8*)(ws + 487424);               // 134217728 B [b][l][t][32]
  u8*    SBT3 = (u8*)(ws + 487424 + 134217728);   //  67108864 B [b][l][t][16]
  u16*   s3b  = (u16*)(ws + 487424 + 134217728 + 67108864);  // 33554432 B u16 [b][co][l]
  // total: 235,368,448 B

  prep_kernel<<<dim3(596), dim3(256), 0, stream>>>(W2, W3, fw1, fw2, A2c, A3c, fw1T, fw2T);
  conv1_lif_kernel<<<dim3(2048, 16), dim3(256), 0, stream>>>(x, W1, b1, SBT2);
  conv_mfma_kernel<256, 128, true><<<dim3(2048, 8, 2), dim3(256), 0, stream>>>(SBT2, A2c, b2, SBT3);
  conv_mfma_kernel<128, 64, false><<<dim3(2048, 8, 1), dim3(256), 0, stream>>>(SBT3, A3c, b3, s3b);
  head_kernel<<<dim3(2048), dim3(256), 0, stream>>>(s3b, W4, b4, fw1T, fb1, fw2T, fb2, out);
}

// Round 15
// 1792.548 us; speedup vs baseline: 1.5735x; 1.5735x over previous
//
#include <hip/hip_runtime.h>
#include <stdint.h>

#define BETA 0.9f

typedef unsigned short u16;
typedef unsigned char u8;
typedef signed char i8;
typedef int i32x4 __attribute__((ext_vector_type(4)));

// async global->LDS, 16B per lane; lds ptr is wave-uniform base (+lane*16 by HW)
__device__ __forceinline__ void async_copy16(const void* g, void* l) {
  __builtin_amdgcn_global_load_lds(
      (const __attribute__((address_space(1))) uint32_t*)g,
      (__attribute__((address_space(3))) uint32_t*)l, 16, 0, 0);
}

// ---------------------------------------------------------------------------
// prep: 3-way int8 fixed-point split of W2/W3 (HW-verified exact):
//   d0 = rint(w*2^11); d1 = rint(r1*2^18); d2 = rint(r2*2^25); res <= 2^-26
// Reconstruction: w*2^25 ~= ((d0<<7)+d1)<<7 + d2 (exact i32 fold).
// Layout A[part][cp][ct][tap][co64][ci64] i8; 12KB DMA blocks; 16-i8 granule
// XOR-swizzled by ((col>>1)&3) for conflict-free b128 LDS reads.
// ---------------------------------------------------------------------------
__global__ void prep_kernel(const float* __restrict__ W2, const float* __restrict__ W3,
                            const float* __restrict__ fw1, const float* __restrict__ fw2,
                            i8* __restrict__ A2c, i8* __restrict__ A3c,
                            float* __restrict__ fw1T, float* __restrict__ fw2T) {
  int o = blockIdx.x * 256 + threadIdx.x;
  if (o < 98304) {  // W2: (tap, co, ci), 3*128*256
    int tap = o >> 15, r = o & 32767, co = r >> 8, ci = r & 255;
    float w = W2[(co * 256 + ci) * 3 + tap];
    float d0 = __builtin_rintf(w * 0x1p11f);
    float r1 = w - d0 * 0x1p-11f;
    float d1 = __builtin_rintf(r1 * 0x1p18f);
    float r2 = r1 - d1 * 0x1p-18f;
    float d2 = __builtin_rintf(r2 * 0x1p25f);
    int cp = ci >> 6, cl = ci & 63;
    int ct = co >> 6, col = co & 63;
    int gs = ((cl >> 4) ^ ((col >> 1) & 3)) & 3;
    int pos = gs * 16 + (cl & 15);
    size_t base = ((size_t)((0 * 4 + cp) * 2 + ct) * 3 + tap) * 64 * 64 + col * 64 + pos;
    size_t pstride = (size_t)4 * 2 * 3 * 64 * 64;  // 98304
    A2c[base] = (i8)(int)d0;
    A2c[pstride + base] = (i8)(int)d1;
    A2c[2 * pstride + base] = (i8)(int)d2;
  }
  int o2 = o - 98304;  // W3: (tap, co, ci), 3*64*128 (NCT=1)
  if (o2 >= 0 && o2 < 24576) {
    int tap = o2 >> 13, r = o2 & 8191, co = r >> 7, ci = r & 127;
    float w = W3[(co * 128 + ci) * 3 + tap];
    float d0 = __builtin_rintf(w * 0x1p11f);
    float r1 = w - d0 * 0x1p-11f;
    float d1 = __builtin_rintf(r1 * 0x1p18f);
    float r2 = r1 - d1 * 0x1p-18f;
    float d2 = __builtin_rintf(r2 * 0x1p25f);
    int cp = ci >> 6, cl = ci & 63;
    int gs = ((cl >> 4) ^ ((co >> 1) & 3)) & 3;
    int pos = gs * 16 + (cl & 15);
    size_t base = ((size_t)(0 * 2 + cp) * 3 + tap) * 64 * 64 + co * 64 + pos;
    size_t pstride = (size_t)2 * 3 * 64 * 64;  // 24576
    A3c[base] = (i8)(int)d0;
    A3c[pstride + base] = (i8)(int)d1;
    A3c[2 * pstride + base] = (i8)(int)d2;
  }
  int o3 = o - (98304 + 24576);
  if (o3 >= 0 && o3 < 25600) {
    int f = o3 / 100, i = o3 % 100;
    fw1T[o3] = fw1[i * 256 + f];
  }
  int o4 = o - (98304 + 24576 + 25600);
  if (o4 >= 0 && o4 < 4000) {
    int i = o4 / 40, j = o4 % 40;
    fw2T[o4] = fw2[j * 100 + i];
  }
}

// ---------------------------------------------------------------------------
// conv1 (2->256, K=5, pad=2) + LIF1 via wave ballot.  [validated r14]
// Block (b, l-octet); wave w holds co = 64w + lane, iterates 8 l's.
// __ballot(spike) at step t IS the byte-transpose. SBT2[b][l][t][g(32)].
// ---------------------------------------------------------------------------
__global__ __launch_bounds__(256) void conv1_lif_kernel(
    const float* __restrict__ x, const float* __restrict__ W1,
    const float* __restrict__ b1, u8* __restrict__ SBT2) {
  __shared__ float xl[2][12];
  int b = blockIdx.x, lb8 = blockIdx.y * 8;
  int tid = threadIdx.x, lane = tid & 63, w = tid >> 6;
  int co = w * 64 + lane;
  if (tid < 24) {
    int ci = tid / 12, idx = tid % 12, lg = lb8 + idx - 2;
    xl[ci][idx] = (lg >= 0 && lg < 128) ? x[(b * 2 + ci) * 128 + lg] : 0.0f;
  }
  float wgt[2][5];
#pragma unroll
  for (int ci = 0; ci < 2; ++ci)
#pragma unroll
    for (int k = 0; k < 5; ++k) wgt[ci][k] = W1[(co * 2 + ci) * 5 + k];
  float bias = b1[co];
  __syncthreads();
  float cur[8];
#pragma unroll
  for (int j = 0; j < 8; ++j) {
    float a = bias;
#pragma unroll
    for (int ci = 0; ci < 2; ++ci)
#pragma unroll
      for (int k = 0; k < 5; ++k) a += wgt[ci][k] * xl[ci][j + k];
    cur[j] = a;
  }
  unsigned long long st0 = 0ull, st1 = 0ull;
#pragma unroll
  for (int l = 0; l < 8; ++l) {
    float m = 0.f, sp = 0.f;
#pragma unroll
    for (int t = 0; t < 16; ++t) {
      m = BETA * m + cur[l] - sp;
      bool s = m > 1.0f;
      unsigned long long bal = __ballot(s);
      int p = l * 16 + t;
      if ((p & 63) == lane) {
        if (p < 64) st0 = bal; else st1 = bal;
      }
      sp = s ? 1.0f : 0.0f;
    }
  }
  int l0 = lane >> 4, t0 = lane & 15;
  *(uint2*)(SBT2 + ((size_t)(b * 128 + lb8 + l0) * 16 + t0) * 32 + w * 8) =
      *(uint2*)&st0;
  *(uint2*)(SBT2 + ((size_t)(b * 128 + lb8 + 4 + l0) * 16 + t0) * 32 + w * 8) =
      *(uint2*)&st1;
}

// ---------------------------------------------------------------------------
// i8 MFMA conv (CIN->COUT, K=3, pad=1) + LIF.  [r13 + packed-B dbuf staging]
// Part-major i8 3-split, single i32 acc, exact <<7 folds; boustrophedon cp
// order (Bf regs persist across part-boundary skips).
// B: per staged cp, the 2304-B PACKED tile [18 row][16 t][8 B] is copied
//    into LDS by 256 threads (2.25 coalesced b32 writes each, conflict-free);
//    lanes read ONE ds_read_u16 per fragment (banks xx*2+(q>>1): clean) and
//    expand in-register. Bs double-buffered -> ONE barrier per v.
// A: async dbuf LDS 12KB/block, granule swizzle. LDS total 29.2 KB.
// ---------------------------------------------------------------------------
template <int CIN, int COUT, bool SBTOUT>
__global__ __launch_bounds__(256, 3) void conv_mfma_kernel(
    const u8* __restrict__ SBT, const i8* __restrict__ Agc,
    const float* __restrict__ bias, void* __restrict__ outp) {
  constexpr int NCP = CIN / 64;            // chunk-pairs (64-ci units)
  constexpr int LNCP = (NCP == 4) ? 2 : 1;
  constexpr int NVIRT = 3 * NCP;
  constexpr int NCT = COUT / 64;
  constexpr int MT = 2, NT = 8;
  constexpr int GB = CIN / 8;              // bytes per (l,t) row in SBT
  constexpr int ABYTES = 3 * 64 * 64;      // 12288 per (part,cp,ct) A block
  constexpr int AW = ABYTES / 4;
  constexpr int AISS = AW / 1024;          // 3
  __shared__ __align__(16) char lds[2 * ABYTES];   // A dbuf; epilogue reuses
  __shared__ __align__(16) u8 Bs[2 * 2304];        // packed B tile, dbuf

  int b = blockIdx.x, lb = blockIdx.y * 16, ct = blockIdx.z;
  int tid = threadIdx.x, lane = tid & 63, wid = tid >> 6;
  int wx = wid & 1, wy = wid >> 1;
  int q = lane >> 4, xx = lane & 15;
  int mloc = wy * 32;
  int gs16 = ((q ^ ((xx >> 1) & 3)) & 3) * 16;  // A swizzled granule (bytes)

  i32x4 acc[MT][NT];
#pragma unroll
  for (int mt = 0; mt < MT; ++mt)
#pragma unroll
    for (int nt = 0; nt < NT; ++nt) acc[mt][nt] = (i32x4){0, 0, 0, 0};

  // staging tasks s in [0,576): row=s>>5, rem=s&31, t=rem>>1, gg=rem&1
  // task copies one u32 of the packed tile; +cp*8 selects the chunk-pair.
  auto mkbase = [&](int s, const u8*& ptr, uint32_t& dstoff, bool& vf) {
    int row = s >> 5, rem = s & 31, t = rem >> 1, gg = rem & 1;
    int l_in = lb + row - 1;
    vf = ((unsigned)l_in < 128u);
    int l_c = vf ? l_in : 0;
    ptr = SBT + ((size_t)(b * 128 + l_c) * 16 + t) * GB + gg * 4;
    dstoff = row * 128 + t * 8 + gg * 4;
  };
  const u8 *sp0, *sp1, *sp2 = nullptr;
  uint32_t do0, do1, do2 = 0;
  bool f0, f1, f2 = false;
  mkbase(tid, sp0, do0, f0);
  mkbase(tid + 256, sp1, do1, f1);
  if (tid < 64) mkbase(tid + 512, sp2, do2, f2);

  auto stage_write = [&](int buf, uint32_t a, uint32_t b2, uint32_t c) {
    u8* base = Bs + buf * 2304;
    *(uint32_t*)(base + do0) = a;
    *(uint32_t*)(base + do1) = b2;
    if (tid < 64) *(uint32_t*)(base + do2) = c;
  };
  auto expand = [&](uint32_t y) -> i32x4 {
    uint32_t b0 = y & 0xFFu, b1 = (y >> 8) & 0xFFu;
    i32x4 r;
    r.x = (int)(((b0 & 0xFu) * 0x204081u) & 0x01010101u);
    r.y = (int)(((b0 >> 4) * 0x204081u) & 0x01010101u);
    r.z = (int)(((b1 & 0xFu) * 0x204081u) & 0x01010101u);
    r.w = (int)(((b1 >> 4) * 0x204081u) & 0x01010101u);
    return r;
  };
  auto ablock = [&](int v) -> size_t {
    int p = v >> LNCP, j = v & (NCP - 1);
    int cp = (p & 1) ? (NCP - 1 - j) : j;
    return ((size_t)(p * NCP + cp) * NCT + ct) * (size_t)ABYTES;
  };

  // prologue: load+write packed tile cp0 into Bs[0]; prefetch next staged
  // cp's sources; issue A-DMA(0).
  uint32_t w4a = f0 ? *(const uint32_t*)sp0 : 0u;
  uint32_t w4b = f1 ? *(const uint32_t*)sp1 : 0u;
  uint32_t w4c = (tid < 64 && f2) ? *(const uint32_t*)sp2 : 0u;
  stage_write(0, w4a, w4b, w4c);
  {  // next staged after (0,0) is (0,1): cp = 1 (fwd)  [conv3: cp1 too]
    int cpn = 1;
    w4a = f0 ? *(const uint32_t*)(sp0 + cpn * 8) : 0u;
    w4b = f1 ? *(const uint32_t*)(sp1 + cpn * 8) : 0u;
    if (tid < 64) w4c = f2 ? *(const uint32_t*)(sp2 + cpn * 8) : 0u;
  }
  {
    const char* gsrc = (const char*)Agc + (size_t)wid * AW + lane * 16 + ablock(0);
    char* ldst = lds + wid * AW;
#pragma unroll
    for (int i = 0; i < AISS; ++i) async_copy16(gsrc + i * 1024, ldst + i * 1024);
  }

  i32x4 Bf[10];
  int sbuf = 0;
  for (int v = 0; v < NVIRT; ++v) {
    int p = v >> LNCP, j = v & (NCP - 1);
    bool stg = (v == 0) || (j != 0);
    __syncthreads();  // drains A-DMA(v) + Bs writes from previous iteration
    if (v + 1 < NVIRT) {
      const char* gsrc = (const char*)Agc + (size_t)wid * AW + lane * 16 + ablock(v + 1);
      char* ldst = lds + ((v + 1) & 1) * ABYTES + wid * AW;
#pragma unroll
      for (int i = 0; i < AISS; ++i) async_copy16(gsrc + i * 1024, ldst + i * 1024);
    }
    if (stg) {
      // read + expand current cp's fragments from Bs[sbuf]
      const u8* bp = Bs + sbuf * 2304 + xx * 8 + 2 * q;
#pragma unroll
      for (int u = 0; u < 10; ++u)
        Bf[u] = expand((uint32_t)*(const u16*)(bp + (wx * 8 + u) * 128));
      // write NEXT staged cp (regs w4*) into Bs[sbuf^1]; prefetch next-next
      int jn = j + 1, pn = p;
      if (jn == NCP) { pn = p + 1; jn = 1; }
      if (pn < 3) {
        stage_write(sbuf ^ 1, w4a, w4b, w4c);
        int jn2 = jn + 1, pn2 = pn;
        if (jn2 == NCP) { pn2 = pn + 1; jn2 = 1; }
        if (pn2 < 3) {
          int cpn2 = (pn2 & 1) ? (NCP - 1 - jn2) : jn2;
          w4a = f0 ? *(const uint32_t*)(sp0 + cpn2 * 8) : 0u;
          w4b = f1 ? *(const uint32_t*)(sp1 + cpn2 * 8) : 0u;
          if (tid < 64) w4c = f2 ? *(const uint32_t*)(sp2 + cpn2 * 8) : 0u;
        }
      }
      sbuf ^= 1;
    }
    if (j == 0 && p > 0) {  // part boundary: exact fold
#pragma unroll
      for (int mt = 0; mt < MT; ++mt)
#pragma unroll
        for (int nt = 0; nt < NT; ++nt) acc[mt][nt] = acc[mt][nt] << 7;
    }
    const i8* Asv = (const i8*)(lds + (v & 1) * ABYTES);
#pragma unroll
    for (int tap = 0; tap < 3; ++tap)
#pragma unroll
      for (int mt = 0; mt < MT; ++mt) {
        i32x4 Af = *(const i32x4*)(Asv + (tap * 64 + mloc + mt * 16 + xx) * 64 + gs16);
#pragma unroll
        for (int nt = 0; nt < NT; ++nt)
          acc[mt][nt] = __builtin_amdgcn_mfma_i32_16x16x64_i8(
              Af, Bf[nt + tap], acc[mt][nt], 0, 0, 0);
      }
  }
  __syncthreads();

  // epilogue: scale 2^-25, per-wave scr transpose (stride 19), LIF, pack
  float* scr = (float*)(void*)lds + wid * 1216;  // 64 rows x 19 words
  u16* blx = (u16*)(lds + 19456);  // SBTOUT: [16 l][64 co]; else [64 co][16 l]
#pragma unroll
  for (int mt = 0; mt < MT; ++mt) {
#pragma unroll
    for (int h = 0; h < 2; ++h) {
#pragma unroll
      for (int u2 = 0; u2 < 4; ++u2)
#pragma unroll
        for (int r = 0; r < 4; ++r)
          scr[(u2 * 16 + q * 4 + r) * 19 + xx] =
              (float)acc[mt][h * 4 + u2][r] * 0x1p-25f;
      __syncthreads();
      int col = mloc + mt * 16 + xx;
      float bc = bias[ct * 64 + col];
      const float* rowp = scr + (q * 16 + xx) * 19;
      float mm = 0.f, sp = 0.f;
      uint32_t bits = 0;
#pragma unroll
      for (int t = 0; t < 16; ++t) {
        float cur = rowp[t] + bc;
        mm = BETA * mm + cur - sp;
        bool s = mm > 1.0f;
        bits |= ((uint32_t)s) << t;
        sp = s ? 1.0f : 0.0f;
      }
      int ll = wx * 8 + h * 4 + q;
      if constexpr (SBTOUT) blx[ll * 64 + col] = (u16)bits;
      else                  blx[col * 16 + ll] = (u16)bits;
      __syncthreads();
    }
  }

  if constexpr (SBTOUT) {
    // thread = (l, t): build 8 bytes (g 0..8) -> [b][l][t][16] at ct*8
    int l = tid >> 4, t = tid & 15;
    uint4 rows[8];
#pragma unroll
    for (int r = 0; r < 8; ++r) rows[r] = *(const uint4*)(blx + l * 64 + r * 8);
    uint32_t lo = 0, hi = 0;
#pragma unroll
    for (int g = 0; g < 8; ++g) {
      uint32_t wv[4] = {rows[g].x, rows[g].y, rows[g].z, rows[g].w};
      uint32_t by = 0;
#pragma unroll
      for (int j2 = 0; j2 < 8; ++j2) {
        uint32_t h16 = (wv[j2 >> 1] >> (16 * (j2 & 1))) & 0xFFFFu;
        by |= ((h16 >> t) & 1u) << j2;
      }
      if (g < 4) lo |= by << (8 * g);
      else       hi |= by << (8 * (g - 4));
    }
    *(uint2*)((u8*)outp + ((size_t)(b * 128 + lb + l) * 16 + t) * 16 + ct * 8) =
        make_uint2(lo, hi);
  } else {
    if (tid < 128) {  // 64 co x 2 halves of 8 l (16B each) -> u16 rows
      int col = tid >> 1, hf = tid & 1;
      uint4 v = *(const uint4*)(blx + col * 16 + hf * 8);
      *(uint4*)((u16*)outp + ((size_t)b * COUT + ct * 64 + col) * 128 + lb + hf * 8) = v;
    }
  }
}

// ---------------------------------------------------------------------------
// head: conv4 (64->2) + LIF4; fc1 (256->100) split across 2 f-halves (200
// active threads, LDS partial reduce) + LIF5; fc2 accumulated (popcount).
// ---------------------------------------------------------------------------
__global__ __launch_bounds__(256) void head_kernel(
    const u16* __restrict__ s3bits, const float* __restrict__ W4,
    const float* __restrict__ b4, const float* __restrict__ fw1T,
    const float* __restrict__ fb1, const float* __restrict__ fw2T,
    const float* __restrict__ fb2, float* __restrict__ out) {
  __shared__ u16 s3l[64][130];
  __shared__ float W4l[384];
  __shared__ u16 flat4[256];
  __shared__ u16 s5b[100];
  int b = blockIdx.x, tid = threadIdx.x;

  for (int i = tid; i < 64 * 130; i += 256) {
    int ci = i / 130, idx = i % 130, lg = idx - 1;
    s3l[ci][idx] = (lg >= 0 && lg < 128) ? s3bits[((size_t)b * 64 + ci) * 128 + lg] : (u16)0;
  }
  for (int i = tid; i < 384; i += 256) W4l[i] = W4[i];
  __syncthreads();

  {
    int co = tid >> 7, l = tid & 127;
    float acc4[16];
#pragma unroll
    for (int t = 0; t < 16; ++t) acc4[t] = 0.f;
    for (int ci = 0; ci < 64; ++ci) {
#pragma unroll
      for (int k = 0; k < 3; ++k) {
        float wv = W4l[(co * 64 + ci) * 3 + k];
        uint32_t msk = s3l[ci][l + k];
#pragma unroll
        for (int t = 0; t < 16; ++t)
          acc4[t] = fmaf(wv, (float)((msk >> t) & 1u), acc4[t]);
      }
    }
    float bc = b4[co];
    float m = 0.f, sp = 0.f;
    uint32_t bits = 0;
#pragma unroll
    for (int t = 0; t < 16; ++t) {
      m = BETA * m + (acc4[t] + bc) - sp;
      bool s = m > 1.0f;
      bits |= ((uint32_t)s) << t;
      sp = s ? 1.0f : 0.0f;
    }
    flat4[tid] = (u16)bits;
  }
  __syncthreads();

  float* part5 = (float*)&s3l[0][0];  // s3l dead; 100*16*4 = 6400 B
  float acc5[16];
#pragma unroll
  for (int t = 0; t < 16; ++t) acc5[t] = 0.f;
  int n5 = tid % 100, h5 = tid / 100;
  if (tid < 200) {
    const float* wp = fw1T + (h5 * 128) * 100 + n5;
    for (int f = 0; f < 128; ++f) {
      float wv = wp[f * 100];
      uint32_t msk = flat4[h5 * 128 + f];
#pragma unroll
      for (int t = 0; t < 16; ++t)
        acc5[t] = fmaf(wv, (float)((msk >> t) & 1u), acc5[t]);
    }
    if (h5 == 1) {
#pragma unroll
      for (int t = 0; t < 16; ++t) part5[n5 * 16 + t] = acc5[t];
    }
  }
  __syncthreads();
  if (tid < 100) {
    float bc = fb1[tid];
    float m = 0.f, sp = 0.f;
    uint32_t bits = 0;
#pragma unroll
    for (int t = 0; t < 16; ++t) {
      float cur = acc5[t] + part5[tid * 16 + t] + bc;
      m = BETA * m + cur - sp;
      bool s = m > 1.0f;
      bits |= ((uint32_t)s) << t;
      sp = s ? 1.0f : 0.0f;
    }
    s5b[tid] = (u16)bits;
  }
  __syncthreads();

  if (tid < 40) {
    float a = 0.f;
    for (int i = 0; i < 100; ++i) {
      float wv = fw2T[i * 40 + tid];
      a = fmaf(wv, (float)__popc((uint32_t)s5b[i]), a);
    }
    out[b * 40 + tid] = a * 0.0625f + fb2[tid];
  }
}

// ---------------------------------------------------------------------------
extern "C" void kernel_launch(void* const* d_in, const int* in_sizes, int n_in,
                              void* d_out, int out_size, void* d_ws, size_t ws_size,
                              hipStream_t stream) {
  const float* x   = (const float*)d_in[0];
  const float* W1  = (const float*)d_in[1];
  const float* b1  = (const float*)d_in[2];
  const float* W2  = (const float*)d_in[3];
  const float* b2  = (const float*)d_in[4];
  const float* W3  = (const float*)d_in[5];
  const float* b3  = (const float*)d_in[6];
  const float* W4  = (const float*)d_in[7];
  const float* b4  = (const float*)d_in[8];
  const float* fw1 = (const float*)d_in[9];
  const float* fb1 = (const float*)d_in[10];
  const float* fw2 = (const float*)d_in[11];
  const float* fb2 = (const float*)d_in[12];
  float* out = (float*)d_out;

  char* ws = (char*)d_ws;
  i8*    A2c  = (i8*)(ws);                        // 294912 B [part][cp][ct][tap][co64][ci64]
  i8*    A3c  = (i8*)(ws + 294912);               //  73728 B
  float* fw1T = (float*)(ws + 368640);            // 102400 B
  float* fw2T = (float*)(ws + 471040);            //  16000 B (pad to 487424)
  u8*    SBT2 = (u8*)(ws + 487424);               // 134217728 B [b][l][t][32]
  u8*    SBT3 = (u8*)(ws + 487424 + 134217728);   //  67108864 B [b][l][t][16]
  u16*   s3b  = (u16*)(ws + 487424 + 134217728 + 67108864);  // 33554432 B u16 [b][co][l]
  // total: 235,368,448 B

  prep_kernel<<<dim3(596), dim3(256), 0, stream>>>(W2, W3, fw1, fw2, A2c, A3c, fw1T, fw2T);
  conv1_lif_kernel<<<dim3(2048, 16), dim3(256), 0, stream>>>(x, W1, b1, SBT2);
  conv_mfma_kernel<256, 128, true><<<dim3(2048, 8, 2), dim3(256), 0, stream>>>(SBT2, A2c, b2, SBT3);
  conv_mfma_kernel<128, 64, false><<<dim3(2048, 8, 1), dim3(256), 0, stream>>>(SBT3, A3c, b3, s3b);
  head_kernel<<<dim3(2048), dim3(256), 0, stream>>>(s3b, W4, b4, fw1T, fb1, fw2T, fb2, out);
}